// Round 4
// baseline (195.593 us; speedup 1.0000x reference)
//
#include <hip/hip_runtime.h>
#include <hip/hip_bf16.h>
#include <stdint.h>

// DCNv2 forward, fixed shapes: N=8, Cin=Cout=256, H=W=Ho=Wo=64, K=3x3, DG=1,
// stride=1, pad=1, dil=1.
//
// R4: software-pipelined fused kernel. colF double-buffered at half-tap
// (128 ch) granularity; per chunk: issue next chunk's gathers -> MFMA current
// chunk -> wait+bilinear+pack+write next buffer -> one barrier. Gather latency
// hides under MFMA within each wave. XCD band swizzle kept from R3.

#define XH 64
#define XW 64
#define CIN 256
#define COUT 256
#define NK 9

typedef __attribute__((ext_vector_type(8))) short short8;   // 8 bf16 (4 VGPRs)
typedef __attribute__((ext_vector_type(4))) float floatx4;
typedef __attribute__((ext_vector_type(2))) float floatx2;
typedef __attribute__((ext_vector_type(4))) int   intx4;

__device__ __forceinline__ short f32_to_bf16_rne(float f) {
    union { float f; uint32_t u; } v; v.f = f;
    uint32_t u = v.u;
    uint32_t r = (u + 0x7FFFu + ((u >> 16) & 1u)) >> 16;
    return (short)(uint16_t)r;
}
__device__ __forceinline__ floatx2 bf16x2_to_f32x2(uint32_t u) {
    union { uint32_t u; float f; } lo, hi;
    lo.u = u << 16;
    hi.u = u & 0xFFFF0000u;
    floatx2 r; r.x = lo.f; r.y = hi.f;
    return r;
}

// ---------------------------------------------------------------------------
// Combined prep (same as R3).
// Blocks [0,512): x (N,C,H,W) f32 -> xT (N,H,W,C) bf16, XCD-swizzled so the
//   XCD that writes rows [8x,8x+8) is the one that reads them in dcn_fused4.
// Blocks [512,800): weight swizzle -> w3 (bf16):
//   w3[(((k*8+ks)*16+mt)*64+lane)*8+j] = W[mt*16+(lane&15)][ks*32+(lane>>4)*8+j][k]
__global__ void dcn_prep(const float* __restrict__ x, const float* __restrict__ w,
                         short* __restrict__ xT, short* __restrict__ w3) {
    int b = blockIdx.x;
    int tid = threadIdx.x;
    if (b < 512) {
        int xcd = b & 7, slot = b >> 3;
        int h = xcd * 8 + (slot & 7);
        int n = slot >> 3;
        int q = tid & 15;        // w-quad
        int cgh = tid >> 4;      // 0..15
        short8* ob = (short8*)(xT + ((size_t)(n * XH + h)) * (XW * CIN));
        for (int it = 0; it < 2; ++it) {
            int cg = cgh + it * 16;          // channel granule 0..31
            const float* xb = x + ((size_t)(n * CIN + cg * 8)) * (XH * XW)
                                + h * XW + q * 4;
            floatx4 r[8];
#pragma unroll
            for (int j = 0; j < 8; ++j)
                r[j] = *(const floatx4*)(xb + (size_t)j * (XH * XW));
#pragma unroll
            for (int jw = 0; jw < 4; ++jw) {
                short8 pk;
#pragma unroll
                for (int j = 0; j < 8; ++j) pk[j] = f32_to_bf16_rne(r[j][jw]);
                ob[(q * 4 + jw) * 32 + cg] = pk;
            }
        }
    } else {
        int gidx = (b - 512) * 256 + tid;    // granule index, < 73728
        int lane = gidx & 63;
        int mt   = (gidx >> 6) & 15;
        int t    = gidx >> 10;               // k*8 + ks
        int ks   = t & 7;
        int k    = t >> 3;
        int co = mt * 16 + (lane & 15);
        int c0 = ks * 32 + (lane >> 4) * 8;
        short8 pk;
#pragma unroll
        for (int j = 0; j < 8; ++j)
            pk[j] = f32_to_bf16_rne(w[(co * CIN + c0 + j) * NK + k]);
        *(short8*)&w3[(size_t)gidx * 8] = pk;
    }
}

// ---------------------------------------------------------------------------
// Pipelined fused kernel. grid = N*Ho = 512, 512 threads (8 waves).
// 18 chunks of (half-tap = 128 ch). Per thread per chunk: 2 items
// (chg16 = tid&15 fixed; pos = it*32 + (tid>>4)), 4 corner gathers each.
__launch_bounds__(512, 4)
__global__ void dcn_fused4(const short* __restrict__ xT,
                           const float* __restrict__ off,
                           const float* __restrict__ msk,
                           const short* __restrict__ w3,
                           const float* __restrict__ bias,
                           float* __restrict__ out) {
    // colF: 2 buffers x 1024 granules of 16B. granule(chg16,pos) at
    //   g = buf*1024 + chg16*64 + (pos ^ (chg16&7))
    __shared__ short   colF[2 * 1024 * 8];   // 32768 B
    __shared__ floatx4 pairW[576];           //  9216 B
    __shared__ intx4   pairO[576];           //  9216 B

    const int bid = blockIdx.x;
    const int xcd = bid & 7, slot = bid >> 3;
    const int ho = xcd * 8 + (slot & 7);     // XCD x owns ho band [8x, 8x+8)
    const int n  = slot >> 3;
    const int tid  = threadIdx.x;
    const int wave = tid >> 6;
    const int lane = tid & 63;

    // ---- bilinear params for 576 (wo, tap) pairs (mask folded) ----
    for (int p = tid; p < 576; p += 512) {
        int wo = p & 63, k = p >> 6;
        int obase = ((n * 18 + 2 * k) * XH + ho) * XW + wo;
        float dy = off[obase];
        float dx = off[obase + XH * XW];
        float mm = msk[((n * NK + k) * XH + ho) * XW + wo];
        float y  = (float)(ho - 1 + k / 3) + dy;
        float xs = (float)(wo - 1 + k % 3) + dx;
        float y0f = floorf(y), x0f = floorf(xs);
        float fy = y - y0f, fx = xs - x0f;
        int y0 = (int)y0f, x0 = (int)x0f;
        float vy0 = (y0 >= 0  && y0 < XH)     ? 1.f : 0.f;
        float vy1 = (y0 >= -1 && y0 < XH - 1) ? 1.f : 0.f;
        float vx0 = (x0 >= 0  && x0 < XW)     ? 1.f : 0.f;
        float vx1 = (x0 >= -1 && x0 < XW - 1) ? 1.f : 0.f;
        floatx4 wv;
        wv.x = (1.f - fy) * (1.f - fx) * mm * vy0 * vx0;
        wv.y = (1.f - fy) * fx         * mm * vy0 * vx1;
        wv.z = fy         * (1.f - fx) * mm * vy1 * vx0;
        wv.w = fy         * fx         * mm * vy1 * vx1;
        int y0c = min(max(y0, 0), XH - 1), y1c = min(max(y0 + 1, 0), XH - 1);
        int x0c = min(max(x0, 0), XW - 1), x1c = min(max(x0 + 1, 0), XW - 1);
        intx4 ov;
        ov.x = y0c * XW + x0c; ov.y = y0c * XW + x1c;
        ov.z = y1c * XW + x0c; ov.w = y1c * XW + x1c;
        pairW[p] = wv;
        pairO[p] = ov;
    }
    __syncthreads();

    floatx4 acc[2][4];
#pragma unroll
    for (int mt = 0; mt < 2; ++mt)
#pragma unroll
        for (int nt = 0; nt < 4; ++nt)
            acc[mt][nt] = (floatx4)(0.f);

    const short8* xTv = (const short8*)(xT + (size_t)n * (XH * XW * CIN));
    const short8* w3v = (const short8*)w3;
    const int quad = lane >> 4, cl = lane & 15;

    const int chg16 = tid & 15;          // fixed granule row (0..15)
    const int posh  = tid >> 4;          // pos = it*32 + posh
    const int sw    = chg16 & 7;

    union U8 { short8 s; uint32_t u[4]; };

    short8  pre[2][4];                   // prefetched corners, 2 items
    floatx4 wv2[2];

    // issue(c): start gathers for chunk c (tap c>>1, half c&1)
    auto issue = [&](int c) {
        int k = c >> 1, half = c & 1;
        int chg = half * 16 + chg16;
#pragma unroll
        for (int it = 0; it < 2; ++it) {
            int p = k * 64 + (it * 32 + posh);
            intx4 ov = pairO[p];
            wv2[it] = pairW[p];
            pre[it][0] = xTv[(size_t)ov.x * 32 + chg];
            pre[it][1] = xTv[(size_t)ov.y * 32 + chg];
            pre[it][2] = xTv[(size_t)ov.z * 32 + chg];
            pre[it][3] = xTv[(size_t)ov.w * 32 + chg];
        }
    };
    // process(c): bilinear combine + pack + write colF buffer (c&1)
    auto process = [&](int c) {
        int half = c & 1;
#pragma unroll
        for (int it = 0; it < 2; ++it) {
            floatx4 wv = wv2[it];
            U8 s0, s1, s2, s3, pk;
            s0.s = pre[it][0]; s1.s = pre[it][1];
            s2.s = pre[it][2]; s3.s = pre[it][3];
#pragma unroll
            for (int i = 0; i < 4; ++i) {
                floatx2 v = bf16x2_to_f32x2(s0.u[i]) * wv.x
                          + bf16x2_to_f32x2(s1.u[i]) * wv.y
                          + bf16x2_to_f32x2(s2.u[i]) * wv.z
                          + bf16x2_to_f32x2(s3.u[i]) * wv.w;
                float2 ff; ff.x = v.x; ff.y = v.y;
                __hip_bfloat162 hb = __float22bfloat162_rn(ff);
                __builtin_memcpy(&pk.u[i], &hb, 4);
            }
            int pos = it * 32 + posh;
            int g = half * 1024 + chg16 * 64 + (pos ^ sw);
            *(short8*)&colF[g * 8] = pk.s;
        }
    };

    // prologue: fill buffer 0 with chunk 0
    issue(0);
    process(0);
    __syncthreads();

    for (int c = 0; c < 18; ++c) {
        if (c < 17) issue(c + 1);
        // ---- MFMA on chunk c (buffer c&1): 4 K-steps of 32 channels ----
        {
            int k = c >> 1, half = c & 1;
            int base = half * 1024;
#pragma unroll
            for (int ks = 0; ks < 4; ++ks) {
                short8 afrag[2];
#pragma unroll
                for (int mt = 0; mt < 2; ++mt)
                    afrag[mt] = w3v[(((k * 8 + half * 4 + ks) * 16)
                                     + (wave * 2 + mt)) * 64 + lane];
                short8 bfrag[4];
                int cr = ks * 4 + quad;          // granule row being read
                int gb = base + cr * 64, swr = cr & 7;
#pragma unroll
                for (int nt = 0; nt < 4; ++nt)
                    bfrag[nt] = *(const short8*)
                        &colF[(gb + ((nt * 16 + cl) ^ swr)) * 8];
#pragma unroll
                for (int mt = 0; mt < 2; ++mt)
#pragma unroll
                    for (int nt = 0; nt < 4; ++nt)
                        acc[mt][nt] = __builtin_amdgcn_mfma_f32_16x16x32_bf16(
                            afrag[mt], bfrag[nt], acc[mt][nt], 0, 0, 0);
            }
        }
        if (c < 17) process(c + 1);
        __syncthreads();
    }

    // ---- epilogue: D layout col=lane&15 (pos), row=(lane>>4)*4+reg (co) ----
#pragma unroll
    for (int mt = 0; mt < 2; ++mt) {
        int cobase = (wave * 2 + mt) * 16 + quad * 4;
#pragma unroll
        for (int r = 0; r < 4; ++r) {
            int co = cobase + r;
            float b = bias[co];
            float* op = out + (((size_t)n * COUT + co) * XH + ho) * XW;
#pragma unroll
            for (int nt = 0; nt < 4; ++nt)
                op[nt * 16 + cl] = acc[mt][nt][r] + b;
        }
    }
}

// ---------------------------------------------------------------------------
// Fallback: naive (ws too small).
__global__ void dcn_naive(const float* __restrict__ x,
                          const float* __restrict__ off,
                          const float* __restrict__ msk,
                          const float* __restrict__ w,
                          const float* __restrict__ bias,
                          float* __restrict__ out) {
    int idx = blockIdx.x * 256 + threadIdx.x;
    if (idx >= 8 * COUT * XH * XW) return;
    int wo = idx & 63, ho = (idx >> 6) & 63, co = (idx >> 12) & 255, n = idx >> 20;
    float acc = bias[co];
    for (int k = 0; k < NK; ++k) {
        int obase = ((n * 18 + 2 * k) * XH + ho) * XW + wo;
        float dy = off[obase];
        float dx = off[obase + XH * XW];
        float mm = msk[((n * NK + k) * XH + ho) * XW + wo];
        float y  = (float)(ho - 1 + k / 3) + dy;
        float xs = (float)(wo - 1 + k % 3) + dx;
        float y0f = floorf(y), x0f = floorf(xs);
        float fy = y - y0f, fx = xs - x0f;
        int y0 = (int)y0f, x0 = (int)x0f;
        float vy0 = (y0 >= 0  && y0 < XH)     ? 1.f : 0.f;
        float vy1 = (y0 >= -1 && y0 < XH - 1) ? 1.f : 0.f;
        float vx0 = (x0 >= 0  && x0 < XW)     ? 1.f : 0.f;
        float vx1 = (x0 >= -1 && x0 < XW - 1) ? 1.f : 0.f;
        float w00 = (1.f - fy) * (1.f - fx) * mm * vy0 * vx0;
        float w01 = (1.f - fy) * fx         * mm * vy0 * vx1;
        float w10 = fy         * (1.f - fx) * mm * vy1 * vx0;
        float w11 = fy         * fx         * mm * vy1 * vx1;
        int y0c = min(max(y0, 0), XH - 1), y1c = min(max(y0 + 1, 0), XH - 1);
        int x0c = min(max(x0, 0), XW - 1), x1c = min(max(x0 + 1, 0), XW - 1);
        int o00 = y0c * XW + x0c, o01 = y0c * XW + x1c;
        int o10 = y1c * XW + x0c, o11 = y1c * XW + x1c;
        for (int c = 0; c < CIN; ++c) {
            const float* xp = x + ((size_t)(n * CIN + c)) * (XH * XW);
            float v = w00 * xp[o00] + w01 * xp[o01] + w10 * xp[o10] + w11 * xp[o11];
            acc += v * w[(co * CIN + c) * NK + k];
        }
    }
    out[idx] = acc;
}

// ---------------------------------------------------------------------------
extern "C" void kernel_launch(void* const* d_in, const int* in_sizes, int n_in,
                              void* d_out, int out_size, void* d_ws, size_t ws_size,
                              hipStream_t stream) {
    const float* x    = (const float*)d_in[0];
    const float* off  = (const float*)d_in[1];
    const float* msk  = (const float*)d_in[2];
    const float* w    = (const float*)d_in[3];
    const float* bias = (const float*)d_in[4];
    float* out = (float*)d_out;

    const size_t W3_BYTES = (size_t)9 * 8 * 16 * 64 * 8 * sizeof(short); // 1179648
    const size_t XT_BYTES = (size_t)8 * XH * XW * CIN * sizeof(short);   // 16777216

    if (ws_size >= W3_BYTES + XT_BYTES) {
        short* w3 = (short*)d_ws;
        short* xT = (short*)((char*)d_ws + W3_BYTES);
        dcn_prep<<<512 + 288, 256, 0, stream>>>(x, w, xT, w3);
        dcn_fused4<<<8 * 64, 512, 0, stream>>>(xT, off, msk, w3, bias, out);
    } else {
        dcn_naive<<<(8 * COUT * XH * XW + 255) / 256, 256, 0, stream>>>(
            x, off, msk, w, bias, out);
    }
}

// Round 5
// 154.171 us; speedup vs baseline: 1.2687x; 1.2687x over previous
//
#include <hip/hip_runtime.h>
#include <hip/hip_bf16.h>
#include <stdint.h>

// DCNv2 forward, fixed shapes: N=8, Cin=Cout=256, H=W=Ho=Wo=64, K=3x3, DG=1,
// stride=1, pad=1, dil=1.
//
// R5: half-tap LDS double-buffer, ONE barrier per chunk, loads consumed
// immediately inside process() (no registers live across barriers -- R4's
// register prefetch spilled to scratch, 64KB/block, thrashing L2).
// Order per chunk: MFMA(c) -> process(c+1) -> barrier. XCD band swizzle kept.

#define XH 64
#define XW 64
#define CIN 256
#define COUT 256
#define NK 9

typedef __attribute__((ext_vector_type(8))) short short8;   // 8 bf16 (4 VGPRs)
typedef __attribute__((ext_vector_type(4))) float floatx4;
typedef __attribute__((ext_vector_type(2))) float floatx2;
typedef __attribute__((ext_vector_type(4))) int   intx4;

__device__ __forceinline__ short f32_to_bf16_rne(float f) {
    union { float f; uint32_t u; } v; v.f = f;
    uint32_t u = v.u;
    uint32_t r = (u + 0x7FFFu + ((u >> 16) & 1u)) >> 16;
    return (short)(uint16_t)r;
}
__device__ __forceinline__ floatx2 bf16x2_to_f32x2(uint32_t u) {
    union { uint32_t u; float f; } lo, hi;
    lo.u = u << 16;
    hi.u = u & 0xFFFF0000u;
    floatx2 r; r.x = lo.f; r.y = hi.f;
    return r;
}

// ---------------------------------------------------------------------------
// Combined prep (same as R3).
// Blocks [0,512): x (N,C,H,W) f32 -> xT (N,H,W,C) bf16, XCD-swizzled so the
//   XCD that writes rows [8x,8x+8) is the one that reads them in dcn_fused5.
// Blocks [512,800): weight swizzle -> w3 (bf16):
//   w3[(((k*8+ks)*16+mt)*64+lane)*8+j] = W[mt*16+(lane&15)][ks*32+(lane>>4)*8+j][k]
__global__ void dcn_prep(const float* __restrict__ x, const float* __restrict__ w,
                         short* __restrict__ xT, short* __restrict__ w3) {
    int b = blockIdx.x;
    int tid = threadIdx.x;
    if (b < 512) {
        int xcd = b & 7, slot = b >> 3;
        int h = xcd * 8 + (slot & 7);
        int n = slot >> 3;
        int q = tid & 15;        // w-quad
        int cgh = tid >> 4;      // 0..15
        short8* ob = (short8*)(xT + ((size_t)(n * XH + h)) * (XW * CIN));
        for (int it = 0; it < 2; ++it) {
            int cg = cgh + it * 16;          // channel granule 0..31
            const float* xb = x + ((size_t)(n * CIN + cg * 8)) * (XH * XW)
                                + h * XW + q * 4;
            floatx4 r[8];
#pragma unroll
            for (int j = 0; j < 8; ++j)
                r[j] = *(const floatx4*)(xb + (size_t)j * (XH * XW));
#pragma unroll
            for (int jw = 0; jw < 4; ++jw) {
                short8 pk;
#pragma unroll
                for (int j = 0; j < 8; ++j) pk[j] = f32_to_bf16_rne(r[j][jw]);
                ob[(q * 4 + jw) * 32 + cg] = pk;
            }
        }
    } else {
        int gidx = (b - 512) * 256 + tid;    // granule index, < 73728
        int lane = gidx & 63;
        int mt   = (gidx >> 6) & 15;
        int t    = gidx >> 10;               // k*8 + ks
        int ks   = t & 7;
        int k    = t >> 3;
        int co = mt * 16 + (lane & 15);
        int c0 = ks * 32 + (lane >> 4) * 8;
        short8 pk;
#pragma unroll
        for (int j = 0; j < 8; ++j)
            pk[j] = f32_to_bf16_rne(w[(co * CIN + c0 + j) * NK + k]);
        *(short8*)&w3[(size_t)gidx * 8] = pk;
    }
}

// ---------------------------------------------------------------------------
// Pipelined fused kernel. grid = N*Ho = 512, 512 threads (8 waves).
// 18 chunks of (half-tap = 128 ch). colF double-buffered (2 x 16KB).
// Per chunk: MFMA(c) from buf c&1, then gather+process chunk c+1 into buf
// (c+1)&1 (loads consumed immediately -> no cross-barrier liveness), barrier.
__launch_bounds__(512, 4)
__global__ void dcn_fused5(const short* __restrict__ xT,
                           const float* __restrict__ off,
                           const float* __restrict__ msk,
                           const short* __restrict__ w3,
                           const float* __restrict__ bias,
                           float* __restrict__ out) {
    // colF granule (buf, chg16, pos) at g = buf*1024 + chg16*64 + (pos^(chg16&7))
    __shared__ short   colF[2 * 1024 * 8];   // 32768 B
    __shared__ floatx4 pairW[576];           //  9216 B
    __shared__ intx4   pairO[576];           //  9216 B

    const int bid = blockIdx.x;
    const int xcd = bid & 7, slot = bid >> 3;
    const int ho = xcd * 8 + (slot & 7);     // XCD x owns ho band [8x, 8x+8)
    const int n  = slot >> 3;
    const int tid  = threadIdx.x;
    const int wave = tid >> 6;
    const int lane = tid & 63;

    // ---- bilinear params for 576 (wo, tap) pairs (mask folded) ----
    for (int p = tid; p < 576; p += 512) {
        int wo = p & 63, k = p >> 6;
        int obase = ((n * 18 + 2 * k) * XH + ho) * XW + wo;
        float dy = off[obase];
        float dx = off[obase + XH * XW];
        float mm = msk[((n * NK + k) * XH + ho) * XW + wo];
        float y  = (float)(ho - 1 + k / 3) + dy;
        float xs = (float)(wo - 1 + k % 3) + dx;
        float y0f = floorf(y), x0f = floorf(xs);
        float fy = y - y0f, fx = xs - x0f;
        int y0 = (int)y0f, x0 = (int)x0f;
        float vy0 = (y0 >= 0  && y0 < XH)     ? 1.f : 0.f;
        float vy1 = (y0 >= -1 && y0 < XH - 1) ? 1.f : 0.f;
        float vx0 = (x0 >= 0  && x0 < XW)     ? 1.f : 0.f;
        float vx1 = (x0 >= -1 && x0 < XW - 1) ? 1.f : 0.f;
        floatx4 wv;
        wv.x = (1.f - fy) * (1.f - fx) * mm * vy0 * vx0;
        wv.y = (1.f - fy) * fx         * mm * vy0 * vx1;
        wv.z = fy         * (1.f - fx) * mm * vy1 * vx0;
        wv.w = fy         * fx         * mm * vy1 * vx1;
        int y0c = min(max(y0, 0), XH - 1), y1c = min(max(y0 + 1, 0), XH - 1);
        int x0c = min(max(x0, 0), XW - 1), x1c = min(max(x0 + 1, 0), XW - 1);
        intx4 ov;
        ov.x = y0c * XW + x0c; ov.y = y0c * XW + x1c;
        ov.z = y1c * XW + x0c; ov.w = y1c * XW + x1c;
        pairW[p] = wv;
        pairO[p] = ov;
    }
    __syncthreads();

    floatx4 acc[2][4];
#pragma unroll
    for (int mt = 0; mt < 2; ++mt)
#pragma unroll
        for (int nt = 0; nt < 4; ++nt)
            acc[mt][nt] = (floatx4)(0.f);

    const short8* xTv = (const short8*)(xT + (size_t)n * (XH * XW * CIN));
    const short8* w3v = (const short8*)w3;
    const int quad = lane >> 4, cl = lane & 15;

    union U8 { short8 s; uint32_t u[4]; };

    // process(c): gather + bilinear + pack + write colF buf (c&1).
    // 1024 items (64 pos x 16 chg16), 2 per thread; loads used immediately.
    auto process = [&](int c) {
        int k = c >> 1, half = c & 1;
        int base = half * 1024;
#pragma unroll
        for (int it = 0; it < 2; ++it) {
            int idx = it * 512 + tid;
            int chg16 = idx & 15;
            int pos   = idx >> 4;
            int p = k * 64 + pos;
            floatx4 wv = pairW[p];
            intx4   ov = pairO[p];
            int chg = half * 16 + chg16;
            U8 s0, s1, s2, s3, pk;
            s0.s = xTv[(size_t)ov.x * 32 + chg];
            s1.s = xTv[(size_t)ov.y * 32 + chg];
            s2.s = xTv[(size_t)ov.z * 32 + chg];
            s3.s = xTv[(size_t)ov.w * 32 + chg];
#pragma unroll
            for (int i = 0; i < 4; ++i) {
                floatx2 v = bf16x2_to_f32x2(s0.u[i]) * wv.x
                          + bf16x2_to_f32x2(s1.u[i]) * wv.y
                          + bf16x2_to_f32x2(s2.u[i]) * wv.z
                          + bf16x2_to_f32x2(s3.u[i]) * wv.w;
                float2 ff; ff.x = v.x; ff.y = v.y;
                __hip_bfloat162 hb = __float22bfloat162_rn(ff);
                __builtin_memcpy(&pk.u[i], &hb, 4);
            }
            int g = base + chg16 * 64 + (pos ^ (chg16 & 7));
            *(short8*)&colF[g * 8] = pk.s;
        }
    };

    // prologue: fill buffer 0 with chunk 0
    process(0);
    __syncthreads();

    for (int c = 0; c < 18; ++c) {
        // ---- MFMA on chunk c (buffer c&1): 4 K-steps of 32 channels ----
        {
            int k = c >> 1, half = c & 1;
            int base = half * 1024;
#pragma unroll
            for (int ks = 0; ks < 4; ++ks) {
                short8 afrag[2];
#pragma unroll
                for (int mt = 0; mt < 2; ++mt)
                    afrag[mt] = w3v[(((k * 8 + half * 4 + ks) * 16)
                                     + (wave * 2 + mt)) * 64 + lane];
                short8 bfrag[4];
                int cr = ks * 4 + quad;          // granule row being read
                int gb = base + cr * 64, swr = cr & 7;
#pragma unroll
                for (int nt = 0; nt < 4; ++nt)
                    bfrag[nt] = *(const short8*)
                        &colF[(gb + ((nt * 16 + cl) ^ swr)) * 8];
#pragma unroll
                for (int mt = 0; mt < 2; ++mt)
#pragma unroll
                    for (int nt = 0; nt < 4; ++nt)
                        acc[mt][nt] = __builtin_amdgcn_mfma_f32_16x16x32_bf16(
                            afrag[mt], bfrag[nt], acc[mt][nt], 0, 0, 0);
            }
        }
        if (c < 17) {
            process(c + 1);
            __syncthreads();
        }
    }

    // ---- epilogue: D layout col=lane&15 (pos), row=(lane>>4)*4+reg (co) ----
#pragma unroll
    for (int mt = 0; mt < 2; ++mt) {
        int cobase = (wave * 2 + mt) * 16 + quad * 4;
#pragma unroll
        for (int r = 0; r < 4; ++r) {
            int co = cobase + r;
            float b = bias[co];
            float* op = out + (((size_t)n * COUT + co) * XH + ho) * XW;
#pragma unroll
            for (int nt = 0; nt < 4; ++nt)
                op[nt * 16 + cl] = acc[mt][nt][r] + b;
        }
    }
}

// ---------------------------------------------------------------------------
// Fallback: naive (ws too small).
__global__ void dcn_naive(const float* __restrict__ x,
                          const float* __restrict__ off,
                          const float* __restrict__ msk,
                          const float* __restrict__ w,
                          const float* __restrict__ bias,
                          float* __restrict__ out) {
    int idx = blockIdx.x * 256 + threadIdx.x;
    if (idx >= 8 * COUT * XH * XW) return;
    int wo = idx & 63, ho = (idx >> 6) & 63, co = (idx >> 12) & 255, n = idx >> 20;
    float acc = bias[co];
    for (int k = 0; k < NK; ++k) {
        int obase = ((n * 18 + 2 * k) * XH + ho) * XW + wo;
        float dy = off[obase];
        float dx = off[obase + XH * XW];
        float mm = msk[((n * NK + k) * XH + ho) * XW + wo];
        float y  = (float)(ho - 1 + k / 3) + dy;
        float xs = (float)(wo - 1 + k % 3) + dx;
        float y0f = floorf(y), x0f = floorf(xs);
        float fy = y - y0f, fx = xs - x0f;
        int y0 = (int)y0f, x0 = (int)x0f;
        float vy0 = (y0 >= 0  && y0 < XH)     ? 1.f : 0.f;
        float vy1 = (y0 >= -1 && y0 < XH - 1) ? 1.f : 0.f;
        float vx0 = (x0 >= 0  && x0 < XW)     ? 1.f : 0.f;
        float vx1 = (x0 >= -1 && x0 < XW - 1) ? 1.f : 0.f;
        float w00 = (1.f - fy) * (1.f - fx) * mm * vy0 * vx0;
        float w01 = (1.f - fy) * fx         * mm * vy0 * vx1;
        float w10 = fy         * (1.f - fx) * mm * vy1 * vx0;
        float w11 = fy         * fx         * mm * vy1 * vx1;
        int y0c = min(max(y0, 0), XH - 1), y1c = min(max(y0 + 1, 0), XH - 1);
        int x0c = min(max(x0, 0), XW - 1), x1c = min(max(x0 + 1, 0), XW - 1);
        int o00 = y0c * XW + x0c, o01 = y0c * XW + x1c;
        int o10 = y1c * XW + x0c, o11 = y1c * XW + x1c;
        for (int c = 0; c < CIN; ++c) {
            const float* xp = x + ((size_t)(n * CIN + c)) * (XH * XW);
            float v = w00 * xp[o00] + w01 * xp[o01] + w10 * xp[o10] + w11 * xp[o11];
            acc += v * w[(co * CIN + c) * NK + k];
        }
    }
    out[idx] = acc;
}

// ---------------------------------------------------------------------------
extern "C" void kernel_launch(void* const* d_in, const int* in_sizes, int n_in,
                              void* d_out, int out_size, void* d_ws, size_t ws_size,
                              hipStream_t stream) {
    const float* x    = (const float*)d_in[0];
    const float* off  = (const float*)d_in[1];
    const float* msk  = (const float*)d_in[2];
    const float* w    = (const float*)d_in[3];
    const float* bias = (const float*)d_in[4];
    float* out = (float*)d_out;

    const size_t W3_BYTES = (size_t)9 * 8 * 16 * 64 * 8 * sizeof(short); // 1179648
    const size_t XT_BYTES = (size_t)8 * XH * XW * CIN * sizeof(short);   // 16777216

    if (ws_size >= W3_BYTES + XT_BYTES) {
        short* w3 = (short*)d_ws;
        short* xT = (short*)((char*)d_ws + W3_BYTES);
        dcn_prep<<<512 + 288, 256, 0, stream>>>(x, w, xT, w3);
        dcn_fused5<<<8 * 64, 512, 0, stream>>>(xT, off, msk, w3, bias, out);
    } else {
        dcn_naive<<<(8 * COUT * XH * XW + 255) / 256, 256, 0, stream>>>(
            x, off, msk, w, bias, out);
    }
}